// Round 9
// baseline (29.687 us; speedup 1.0000x reference)
//
#include <hip/hip_runtime.h>

// SimpleRPMGLoss: out = mean(smooth_l1(pred[:,:3], tgt[:,:3]))
//               + 100 * mean(acos(clip((sum(R(pred_e)*R(tgt_e)) - 1)/2)))
// B = 2,097,152 rows x 6 f32 each input (~100 MB read). Streaming reduction at
// the measured MI355X streaming-read ceiling (~5.1 TB/s; cf. RMSNorm/LN 4.9-5.4).
//
// k1 body: proven-fastest simple form (19.7us across ALL variants: occupancy,
// hoisting, asm-pin, LDS staging -- all neutral => memory-system-limited).
//
// Fused single-dispatch with TWO-LEVEL spread arrival counters:
//   Round 6's fused tail (19.5us) was 2048 same-line agent RMWs serialized at
//   ~9.5ns (~23cyc) each at the coherence point. Here: 32 line-counters on
//   separate 64B lines (64 blocks each; arrivals ~300ns apart per line >> 9.5ns
//   service => no queuing) + one 32-arrival master => tail < 0.5us.
//   All atomics RELAXED agent scope (ACQ_REL RMW emits buffer_wbl2/inv per
//   block on gfx950 => 114us in round 3). Visibility: sc1 write-through partial
//   stores -> s_waitcnt vmcnt(0) -> line RMW; line-last's RMW return proves all
//   64 line partials acked; master RMW return proves all lines done.
//   Counter memset is MANDATORY (replay #1 sees 0xAA poison; round 6's
//   no-memset mod-trigger raced the finisher: absmax 1.0).

constexpr int   B_ROWS  = 2097152;
constexpr int   NBLK    = 2048;             // 8 blocks/CU on 256 CUs
constexpr int   TPB     = 256;
constexpr int   NTHREAD = NBLK * TPB;       // 524288 threads; 2 row-pairs each
constexpr int   NLINES  = 32;
constexpr int   BLK_PER_LINE = NBLK / NLINES;   // 64
constexpr int   LINE_STRIDE_U32 = 16;           // 64 B between counters
constexpr float ANGLE_WEIGHT = 100.0f;
constexpr float EPS_F        = 1e-7f;

typedef float f32x4 __attribute__((ext_vector_type(4)));

__device__ inline float smooth_l1_term(float d) {
    float ad = fabsf(d);
    return ad < 1.0f ? 0.5f * d * d : ad - 0.5f;
}

__device__ inline void euler_xyz_mat(float a, float b, float c, float r[9]) {
    float sa, ca, sb, cb, sc, cc;
    __sincosf(a, &sa, &ca);
    __sincosf(b, &sb, &cb);
    __sincosf(c, &sc, &cc);
    r[0] = cb * cc;
    r[1] = cc * sa * sb - ca * sc;
    r[2] = sc * sa + ca * cc * sb;
    r[3] = cb * sc;
    r[4] = ca * cc + sa * sb * sc;
    r[5] = ca * sb * sc - cc * sa;
    r[6] = -sb;
    r[7] = cb * sa;
    r[8] = ca * cb;
}

__device__ inline void accum_row(float px, float py, float pz,
                                 float pa, float pb, float pc,
                                 float tx, float ty, float tz,
                                 float ta, float tb, float tc,
                                 float& trans_acc, float& rot_acc) {
    trans_acc += smooth_l1_term(px - tx) + smooth_l1_term(py - ty) + smooth_l1_term(pz - tz);
    float rp[9], rt[9];
    euler_xyz_mat(pa, pb, pc, rp);
    euler_xyz_mat(ta, tb, tc, rt);
    float tr = 0.0f;
#pragma unroll
    for (int i = 0; i < 9; ++i) tr = fmaf(rp[i], rt[i], tr);
    float cosang = fminf(fmaxf((tr - 1.0f) * 0.5f, -1.0f + EPS_F), 1.0f - EPS_F);
    rot_acc += acosf(cosang);
}

__global__ __launch_bounds__(TPB, 4) void rpmg_fused_kernel(const float* __restrict__ pred,
                                                            const float* __restrict__ tgt,
                                                            float2* __restrict__ partial,
                                                            unsigned int* __restrict__ counters,
                                                            float* __restrict__ out) {
    const int tid = blockIdx.x * TPB + threadIdx.x;
    const f32x4* pp1 = reinterpret_cast<const f32x4*>(pred) + (size_t)tid * 3;
    const f32x4* tp1 = reinterpret_cast<const f32x4*>(tgt)  + (size_t)tid * 3;
    const f32x4* pp2 = pp1 + (size_t)NTHREAD * 3;
    const f32x4* tp2 = tp1 + (size_t)NTHREAD * 3;

    f32x4 a0 = pp1[0], a1 = pp1[1], a2 = pp1[2];
    f32x4 b0 = tp1[0], b1 = tp1[1], b2 = tp1[2];
    f32x4 c0 = pp2[0], c1 = pp2[1], c2 = pp2[2];
    f32x4 d0 = tp2[0], d1 = tp2[1], d2 = tp2[2];

    float trans_acc = 0.0f, rot_acc = 0.0f;
    accum_row(a0[0], a0[1], a0[2], a0[3], a1[0], a1[1],
              b0[0], b0[1], b0[2], b0[3], b1[0], b1[1], trans_acc, rot_acc);
    accum_row(a1[2], a1[3], a2[0], a2[1], a2[2], a2[3],
              b1[2], b1[3], b2[0], b2[1], b2[2], b2[3], trans_acc, rot_acc);
    accum_row(c0[0], c0[1], c0[2], c0[3], c1[0], c1[1],
              d0[0], d0[1], d0[2], d0[3], d1[0], d1[1], trans_acc, rot_acc);
    accum_row(c1[2], c1[3], c2[0], c2[1], c2[2], c2[3],
              d1[2], d1[3], d2[0], d2[1], d2[2], d2[3], trans_acc, rot_acc);

    // Block reduction.
#pragma unroll
    for (int off = 32; off > 0; off >>= 1) {
        trans_acc += __shfl_down(trans_acc, off, 64);
        rot_acc   += __shfl_down(rot_acc,   off, 64);
    }
    __shared__ float sa[TPB / 64], sb[TPB / 64];
    __shared__ int   s_last;
    const int wid  = threadIdx.x >> 6;
    const int lane = threadIdx.x & 63;
    if (lane == 0) { sa[wid] = trans_acc; sb[wid] = rot_acc; }
    __syncthreads();
    if (threadIdx.x == 0) {
        float ta = 0.0f, tb = 0.0f;
#pragma unroll
        for (int w = 0; w < TPB / 64; ++w) { ta += sa[w]; tb += sb[w]; }
        // Partial to coherence point (sc1 write-through, no L2 wb/inv).
        __hip_atomic_store(&partial[blockIdx.x].x, ta, __ATOMIC_RELAXED, __HIP_MEMORY_SCOPE_AGENT);
        __hip_atomic_store(&partial[blockIdx.x].y, tb, __ATOMIC_RELAXED, __HIP_MEMORY_SCOPE_AGENT);
        asm volatile("s_waitcnt vmcnt(0)" ::: "memory");   // partial acked before arrival RMW

        // Level 1: per-line arrival counter (32 lines, 64 blocks each).
        const int line = blockIdx.x & (NLINES - 1);
        unsigned int old = __hip_atomic_fetch_add(&counters[line * LINE_STRIDE_U32], 1u,
                                                  __ATOMIC_RELAXED, __HIP_MEMORY_SCOPE_AGENT);
        int g_last = 0;
        if (old == (unsigned int)(BLK_PER_LINE - 1)) {
            // All 64 blocks of this line have acked their partials. Level 2:
            // master counter (32 arrivals total). RMW result `old` is already
            // waited on (data dependency), ordering the master RMW after it.
            unsigned int old2 = __hip_atomic_fetch_add(&counters[NLINES * LINE_STRIDE_U32], 1u,
                                                       __ATOMIC_RELAXED, __HIP_MEMORY_SCOPE_AGENT);
            g_last = (old2 == (unsigned int)(NLINES - 1)) ? 1 : 0;
        }
        s_last = g_last;
    }
    __syncthreads();

    if (s_last) {
        // Exactly one block per launch; all 2048 partials acked at the
        // coherence point. Fixed-order reduction -> deterministic output.
        float ta = 0.0f, tb = 0.0f;
        for (int i = threadIdx.x; i < NBLK; i += TPB) {
            ta += __hip_atomic_load(&partial[i].x, __ATOMIC_RELAXED, __HIP_MEMORY_SCOPE_AGENT);
            tb += __hip_atomic_load(&partial[i].y, __ATOMIC_RELAXED, __HIP_MEMORY_SCOPE_AGENT);
        }
#pragma unroll
        for (int off = 32; off > 0; off >>= 1) {
            ta += __shfl_down(ta, off, 64);
            tb += __shfl_down(tb, off, 64);
        }
        __syncthreads();   // sa/sb reuse
        if (lane == 0) { sa[wid] = ta; sb[wid] = tb; }
        __syncthreads();
        if (threadIdx.x == 0) {
            float st = 0.0f, sr = 0.0f;
#pragma unroll
            for (int w = 0; w < TPB / 64; ++w) { st += sa[w]; sr += sb[w]; }
            out[0] = st / (3.0f * (float)B_ROWS) + ANGLE_WEIGHT * (sr / (float)B_ROWS);
        }
    }
}

extern "C" void kernel_launch(void* const* d_in, const int* in_sizes, int n_in,
                              void* d_out, int out_size, void* d_ws, size_t ws_size,
                              hipStream_t stream) {
    const float* pred = (const float*)d_in[0];
    const float* tgt  = (const float*)d_in[1];
    float* out        = (float*)d_out;

    float2*       partial  = (float2*)d_ws;                                  // 16 KB
    unsigned int* counters = (unsigned int*)((char*)d_ws + NBLK * sizeof(float2));
    const size_t  counters_bytes = (NLINES * LINE_STRIDE_U32 + 16) * sizeof(unsigned int);

    hipMemsetAsync(counters, 0, counters_bytes, stream);
    rpmg_fused_kernel<<<NBLK, TPB, 0, stream>>>(pred, tgt, partial, counters, out);
}